// Round 1
// baseline (218.733 us; speedup 1.0000x reference)
//
#include <hip/hip_runtime.h>
#include <math.h>

typedef __bf16 bf16_t;
typedef __bf16 bf16x8 __attribute__((ext_vector_type(8)));
typedef float f32x4 __attribute__((ext_vector_type(4)));

#define DIMC 256
#define HEADS 4
#define HDIM 64
#define HID 768
#define NB 8
#define NN 4096
#define ROWS (NB*NN)   /* 32768 */
#define NCHUNK 16

// ---------------- prep: x -> bf16 ----------------
__global__ __launch_bounds__(256) void prep_x_kernel(const float* __restrict__ x,
                                                     bf16_t* __restrict__ xb) {
  int i = (blockIdx.x * 256 + threadIdx.x) * 8;
  f32x4 a = *(const f32x4*)(x + i);
  f32x4 b = *(const f32x4*)(x + i + 4);
  bf16x8 o;
  o[0] = (bf16_t)a[0]; o[1] = (bf16_t)a[1]; o[2] = (bf16_t)a[2]; o[3] = (bf16_t)a[3];
  o[4] = (bf16_t)b[0]; o[5] = (bf16_t)b[1]; o[6] = (bf16_t)b[2]; o[7] = (bf16_t)b[3];
  *(bf16x8*)(xb + i) = o;
}

// ---------------- prep: transpose weight [K][Nw] -> bf16 [Nw][K] ----------------
__global__ __launch_bounds__(256) void transpose_w_kernel(const float* __restrict__ w,
                                                          bf16_t* __restrict__ wt,
                                                          int K, int Nw) {
  int o = blockIdx.x * 256 + threadIdx.x;  // o in [0, Nw*K)
  int n = o / K, k = o - n * K;
  wt[o] = (bf16_t)w[(size_t)k * Nw + n];
}

__device__ __forceinline__ float gelu_exact(float v) {
  return 0.5f * v * (1.0f + erff(v * 0.70710678118654752f));
}

// ---------------- bf16 MFMA GEMM: C[M,N] = A[M,K] * BT[N,K]^T (+epilogue) ----------------
// EPI 0: out bf16 = acc + bias
// EPI 1: out bf16 = gelu(acc + bias)
// EPI 2: out f32  = acc + bias + resid
template <int EPI>
__global__ __launch_bounds__(256)
void gemm_kernel(const bf16_t* __restrict__ A, const bf16_t* __restrict__ BT,
                 const float* __restrict__ bias, void* __restrict__ outp,
                 const float* __restrict__ resid, int N, int K) {
  __shared__ __align__(16) bf16_t ldsA[2][512 * 8];
  __shared__ __align__(16) bf16_t ldsB[2][512 * 8];
  const int tid = threadIdx.x;
  const int m0 = blockIdx.y * 128, n0 = blockIdx.x * 128;
  const int lane = tid & 63, w = tid >> 6;
  const int wr = w >> 1, wc = w & 1;
  const int lr = lane & 15, lk = lane >> 4;

  f32x4 acc[4][4] = {};
  const int ksteps = K >> 5;

  auto stage = [&](int buf, int ks) {
#pragma unroll
    for (int i = 0; i < 2; ++i) {
      int p = i * 256 + tid;
      int row = p & 127, kc = p >> 7;
      const bf16_t* ga = A + (size_t)(m0 + row) * K + ks * 32 + kc * 8;
      __builtin_amdgcn_global_load_lds(
          (const __attribute__((address_space(1))) void*)ga,
          (__attribute__((address_space(3))) void*)&ldsA[buf][p * 8], 16, 0, 0);
      const bf16_t* gb = BT + (size_t)(n0 + row) * K + ks * 32 + kc * 8;
      __builtin_amdgcn_global_load_lds(
          (const __attribute__((address_space(1))) void*)gb,
          (__attribute__((address_space(3))) void*)&ldsB[buf][p * 8], 16, 0, 0);
    }
  };

  auto compute = [&](int buf) {
    const bf16x8* pA = (const bf16x8*)&ldsA[buf][0];
    const bf16x8* pB = (const bf16x8*)&ldsB[buf][0];
    bf16x8 af[4], bfr[4];
#pragma unroll
    for (int mi = 0; mi < 4; ++mi) af[mi] = pA[lk * 128 + wr * 64 + mi * 16 + lr];
#pragma unroll
    for (int ni = 0; ni < 4; ++ni) bfr[ni] = pB[lk * 128 + wc * 64 + ni * 16 + lr];
#pragma unroll
    for (int mi = 0; mi < 4; ++mi)
#pragma unroll
      for (int ni = 0; ni < 4; ++ni)
        acc[mi][ni] = __builtin_amdgcn_mfma_f32_16x16x32_bf16(af[mi], bfr[ni],
                                                              acc[mi][ni], 0, 0, 0);
  };

  stage(0, 0);
  __syncthreads();
  int cur = 0;
  for (int ks = 0; ks < ksteps - 1; ++ks) {
    stage(cur ^ 1, ks + 1);
    compute(cur);
    __syncthreads();
    cur ^= 1;
  }
  compute(cur);

  // epilogue: D row = (lane>>4)*4 + r, col = lane&15 (HW-verified C/D layout)
#pragma unroll
  for (int mi = 0; mi < 4; ++mi) {
    int row_b = m0 + wr * 64 + mi * 16 + lk * 4;
#pragma unroll
    for (int ni = 0; ni < 4; ++ni) {
      int col = n0 + wc * 64 + ni * 16 + lr;
      float bs = bias[col];
      f32x4 v = acc[mi][ni];
#pragma unroll
      for (int r = 0; r < 4; ++r) {
        int row = row_b + r;
        float val = v[r] + bs;
        if (EPI == 1) val = gelu_exact(val);
        size_t off = (size_t)row * N + col;
        if (EPI == 2)
          ((float*)outp)[off] = val + resid[off];
        else
          ((bf16_t*)outp)[off] = (bf16_t)val;
      }
    }
  }
}

// ---------------- attention: partial K^T V over N-chunks ----------------
// part[chunk][bh][d][e] += sum_{n in chunk} k[n][d] * v[n][e]
__global__ __launch_bounds__(256)
void attn_kv_kernel(const bf16_t* __restrict__ qkv, float* __restrict__ part) {
  const int bh = blockIdx.x, chunk = blockIdx.y;
  const int b = bh >> 2, h = bh & 3;
  __shared__ __align__(16) float kl[32][68];
  __shared__ __align__(16) float vl[32][68];
  const int tid = threadIdx.x;
  const int dg = tid >> 4, eg = tid & 15;
  f32x4 acc[4] = {};
  const int rows_per_chunk = NN / NCHUNK;  // 256
  const int n00 = chunk * rows_per_chunk;
  const int srow = tid >> 3, spk = tid & 7;
  for (int t = 0; t < rows_per_chunk / 32; ++t) {
    int n0 = n00 + t * 32;
    {
      const bf16x8 k8 = *(const bf16x8*)(qkv + (size_t)(b * NN + n0 + srow) * HID + 256 + h * 64 + spk * 8);
      const bf16x8 v8 = *(const bf16x8*)(qkv + (size_t)(b * NN + n0 + srow) * HID + 512 + h * 64 + spk * 8);
#pragma unroll
      for (int j = 0; j < 8; ++j) kl[srow][spk * 8 + j] = (float)k8[j];
#pragma unroll
      for (int j = 0; j < 8; ++j) vl[srow][spk * 8 + j] = (float)v8[j];
    }
    __syncthreads();
#pragma unroll 8
    for (int n = 0; n < 32; ++n) {
      f32x4 k4 = *(const f32x4*)&kl[n][dg * 4];
      f32x4 v4 = *(const f32x4*)&vl[n][eg * 4];
#pragma unroll
      for (int i = 0; i < 4; ++i) acc[i] += k4[i] * v4;
    }
    __syncthreads();
  }
  float* dst = part + (size_t)(chunk * 32 + bh) * 4096;
#pragma unroll
  for (int i = 0; i < 4; ++i)
    *(f32x4*)&dst[(dg * 4 + i) * 64 + eg * 4] = acc[i];
}

// ---------------- attention: reduce partials + scale + softmax over e ----------------
__global__ __launch_bounds__(256)
void attn_softmax_kernel(const float* __restrict__ part, float* __restrict__ attn) {
  const int bh = blockIdx.x;
  const int tid = threadIdx.x;
  const int dg = tid >> 4, eg = tid & 15;
  f32x4 s[4] = {};
  for (int c = 0; c < NCHUNK; ++c) {
    const float* src = part + (size_t)(c * 32 + bh) * 4096;
#pragma unroll
    for (int i = 0; i < 4; ++i) s[i] += *(const f32x4*)&src[(dg * 4 + i) * 64 + eg * 4];
  }
  float* dst = attn + (size_t)bh * 4096;
#pragma unroll
  for (int i = 0; i < 4; ++i) {
    f32x4 l = s[i] * 0.125f;  // k-scale = 1/sqrt(64)
    float m = fmaxf(fmaxf(l[0], l[1]), fmaxf(l[2], l[3]));
#pragma unroll
    for (int msk = 1; msk < 16; msk <<= 1) m = fmaxf(m, __shfl_xor(m, msk));
    f32x4 p;
    float sum = 0.f;
#pragma unroll
    for (int j = 0; j < 4; ++j) { p[j] = expf(l[j] - m); sum += p[j]; }
#pragma unroll
    for (int msk = 1; msk < 16; msk <<= 1) sum += __shfl_xor(sum, msk);
    p *= (1.0f / sum);
    *(f32x4*)&dst[(dg * 4 + i) * 64 + eg * 4] = p;
  }
}

// ---------------- xf = Q attn^T, x2 = x + xf, hln = LN(x2) ----------------
__global__ __launch_bounds__(256)
void xf_ln_kernel(const bf16_t* __restrict__ qkv, const float* __restrict__ attn,
                  const float* __restrict__ x, float* __restrict__ x2,
                  bf16_t* __restrict__ hln, const float* __restrict__ gamma,
                  const float* __restrict__ beta) {
  const int row0 = blockIdx.x * 16;
  const int b = row0 >> 12;
  const int tid = threadIdx.x;
  const int c = tid, h = c >> 6, d = c & 63;
  f32x4 arow[16];
  const float* ap = attn + ((size_t)(b * 4 + h) * 64 + d) * 64;
#pragma unroll
  for (int s = 0; s < 16; ++s) arow[s] = *(const f32x4*)&ap[s * 4];
  __shared__ __align__(16) float ql[16][256];
#pragma unroll
  for (int i = 0; i < 2; ++i) {
    int p = i * 256 + tid;
    int r = p >> 5, pk = p & 31;
    bf16x8 q8 = *(const bf16x8*)(qkv + (size_t)(row0 + r) * HID + pk * 8);
#pragma unroll
    for (int j = 0; j < 8; ++j) ql[r][pk * 8 + j] = (float)q8[j];
  }
  __shared__ float red[4][2];
  __syncthreads();
  const float gv = gamma[c], bv = beta[c];
  const int wv = tid >> 6;
  for (int r = 0; r < 16; ++r) {
    float xf = 0.f;
#pragma unroll
    for (int s = 0; s < 16; ++s) {
      f32x4 q4 = *(const f32x4*)&ql[r][h * 64 + s * 4];
      xf += arow[s][0] * q4[0] + arow[s][1] * q4[1] + arow[s][2] * q4[2] + arow[s][3] * q4[3];
    }
    size_t off = (size_t)(row0 + r) * DIMC + c;
    float x2v = x[off] + xf;
    float s1 = x2v, s2 = x2v * x2v;
#pragma unroll
    for (int msk = 1; msk < 64; msk <<= 1) {
      s1 += __shfl_xor(s1, msk);
      s2 += __shfl_xor(s2, msk);
    }
    if ((tid & 63) == 0) { red[wv][0] = s1; red[wv][1] = s2; }
    __syncthreads();
    float t1 = red[0][0] + red[1][0] + red[2][0] + red[3][0];
    float t2 = red[0][1] + red[1][1] + red[2][1] + red[3][1];
    float mu = t1 * (1.0f / 256.0f);
    float var = t2 * (1.0f / 256.0f) - mu * mu;
    float rs = rsqrtf(var + 1e-5f);
    x2[off] = x2v;
    hln[off] = (bf16_t)((x2v - mu) * rs * gv + bv);
    __syncthreads();
  }
}

extern "C" void kernel_launch(void* const* d_in, const int* in_sizes, int n_in,
                              void* d_out, int out_size, void* d_ws, size_t ws_size,
                              hipStream_t stream) {
  const float* x      = (const float*)d_in[0];
  const float* w_qkv  = (const float*)d_in[1];
  const float* b_qkv  = (const float*)d_in[2];
  const float* norm_g = (const float*)d_in[3];
  const float* norm_b = (const float*)d_in[4];
  const float* w_fc1  = (const float*)d_in[5];
  const float* b_fc1  = (const float*)d_in[6];
  const float* w_fc2  = (const float*)d_in[7];
  const float* b_fc2  = (const float*)d_in[8];

  char* ws = (char*)d_ws;
  size_t off = 0;
  bf16_t* qkv   = (bf16_t*)(ws + off); off += (size_t)ROWS * HID * 2;       // 50.3 MB (reused as mid)
  bf16_t* mid   = qkv;
  bf16_t* xb    = (bf16_t*)(ws + off); off += (size_t)ROWS * DIMC * 2;      // 16.8 MB (reused as hln)
  bf16_t* hln   = xb;
  float*  part  = (float*)(ws + off);  off += (size_t)NCHUNK * 32 * 4096 * 4;  // 8.4 MB
  float*  attn  = (float*)(ws + off);  off += (size_t)32 * 4096 * 4;        // 0.5 MB
  float*  x2    = (float*)(ws + off);  off += (size_t)ROWS * DIMC * 4;      // 33.6 MB
  bf16_t* wqkvT = (bf16_t*)(ws + off); off += (size_t)768 * 256 * 2;
  bf16_t* wfc1T = (bf16_t*)(ws + off); off += (size_t)768 * 256 * 2;
  bf16_t* wfc2T = (bf16_t*)(ws + off); off += (size_t)256 * 768 * 2;

  prep_x_kernel<<<(ROWS * DIMC) / (256 * 8), 256, 0, stream>>>(x, xb);
  transpose_w_kernel<<<768, 256, 0, stream>>>(w_qkv, wqkvT, 256, 768);
  transpose_w_kernel<<<768, 256, 0, stream>>>(w_fc1, wfc1T, 256, 768);
  transpose_w_kernel<<<768, 256, 0, stream>>>(w_fc2, wfc2T, 768, 256);

  // qkv = x @ w_qkv + b_qkv            [32768 x 768], K=256
  gemm_kernel<0><<<dim3(6, 256), 256, 0, stream>>>(xb, wqkvT, b_qkv, qkv, nullptr, 768, 256);
  // attn partials + softmax
  attn_kv_kernel<<<dim3(32, NCHUNK), 256, 0, stream>>>(qkv, part);
  attn_softmax_kernel<<<32, 256, 0, stream>>>(part, attn);
  // xf + residual + layernorm
  xf_ln_kernel<<<ROWS / 16, 256, 0, stream>>>(qkv, attn, x, x2, hln, norm_g, norm_b);
  // mid = gelu(hln @ w_fc1 + b_fc1)    [32768 x 768], K=256
  gemm_kernel<1><<<dim3(6, 256), 256, 0, stream>>>(hln, wfc1T, b_fc1, mid, nullptr, 768, 256);
  // out = x2 + mid @ w_fc2 + b_fc2     [32768 x 256], K=768
  gemm_kernel<2><<<dim3(2, 256), 256, 0, stream>>>(mid, wfc2T, b_fc2, d_out, x2, 256, 768);
}